// Round 1
// baseline (184.666 us; speedup 1.0000x reference)
//
#include <hip/hip_runtime.h>

typedef unsigned short u16;
typedef unsigned int u32;
typedef __attribute__((ext_vector_type(4))) float f32x4;
typedef __attribute__((ext_vector_type(8))) __bf16 bf16x8;
typedef __attribute__((ext_vector_type(4))) u16 u16x4;
typedef __attribute__((ext_vector_type(4))) float f32x4v;

#define LSEQ 128
#define KW 8
#define NP 2104
#define BATCH 16
#define MTOT 33664   // BATCH*NP = 263*128
#define FDIM 1088    // PAIR_FEAT
#define GPAD 1152    // 9*128

// ---- workspace layout (bytes) ----
#define WS_W1P  0ul          // u16 [1152*1088] = 2,506,752 B
#define WS_EMOB 2506752ul    // u16 [16*128*512] = 2,097,152 B
#define WS_CAUB 4603904ul    // u16 [16*128*512]
#define WS_SMB  6701056ul    // u16 [17*64] = 2,176 B
#define WS_B1P  6703232ul    // f32 [1152]
#define WS_W2P  6707840ul    // f32 [1152]
#define WS_TABI 6712448ul    // int [2104]
#define WS_TABJ 6720864ul    // int [2104]
#define WS_TABR 6729280ul    // int [2104]  (end 6,737,696)

__device__ __forceinline__ u16 f2bf(float x) {
  union { float f; u32 u; } v; v.f = x;
  u32 r = v.u + 0x7fffu + ((v.u >> 16) & 1u);
  return (u16)(r >> 16);
}

__device__ __forceinline__ void load_lds16(const void* g, void* l) {
  __builtin_amdgcn_global_load_lds(
      (const __attribute__((address_space(1))) void*)g,
      (__attribute__((address_space(3))) void*)l, 16, 0, 0);
}

// ---- W1 fp32 -> bf16, padded to [1152][1088] (pad rows = 0) ----
__global__ void cvt_w1(const float* __restrict__ W1, u16* __restrict__ W1p) {
  int idx = blockIdx.x * 256 + threadIdx.x;   // vec4 units: 1152*272 = 313344
  if (idx >= 313344) return;
  int g = idx / 272;
  int f = (idx - g * 272) * 4;
  u16x4 o;
  if (g < 1088) {
    f32x4v v = *(const f32x4v*)&W1[g * 1088 + f];
    o.x = f2bf(v.x); o.y = f2bf(v.y); o.z = f2bf(v.z); o.w = f2bf(v.w);
  } else {
    o.x = 0; o.y = 0; o.z = 0; o.w = 0;
  }
  *(u16x4*)&W1p[(size_t)g * 1088 + f] = o;
}

// ---- H_emo/H_cause fp32 -> bf16 ; init pred region of d_out to b2 ----
__global__ void cvt_h(const float* __restrict__ emo, const float* __restrict__ cau,
                      const float* __restrict__ b2,
                      u16* __restrict__ emoB, u16* __restrict__ cauB,
                      float* __restrict__ pred) {
  int idx = blockIdx.x * 256 + threadIdx.x;  // vec4 units
  if (idx < 262144) {
    f32x4v v = *(const f32x4v*)&emo[idx * 4];
    u16x4 o; o.x = f2bf(v.x); o.y = f2bf(v.y); o.z = f2bf(v.z); o.w = f2bf(v.w);
    *(u16x4*)&emoB[idx * 4] = o;
  } else if (idx < 524288) {
    int k = idx - 262144;
    f32x4v v = *(const f32x4v*)&cau[k * 4];
    u16x4 o; o.x = f2bf(v.x); o.y = f2bf(v.y); o.z = f2bf(v.z); o.w = f2bf(v.w);
    *(u16x4*)&cauB[k * 4] = o;
  } else {
    int k = idx - 524288;      // 8416 vec4 units cover 33664 floats
    if (k < 8416) {
      float bv = b2[0];
      f32x4v o = {bv, bv, bv, bv};
      *(f32x4v*)&pred[k * 4] = o;
    }
  }
}

// ---- pair tables, smoothed17, padded b1/W2, emo_cau_pos output ----
__global__ void setup_small(const float* __restrict__ pos_emb, const float* __restrict__ b1,
                            const float* __restrict__ W2,
                            int* __restrict__ tab_i, int* __restrict__ tab_j,
                            int* __restrict__ tab_r,
                            u16* __restrict__ sm17, float* __restrict__ b1p,
                            float* __restrict__ w2p, float* __restrict__ out_pos) {
  int t = threadIdx.x;
  if (t < LSEQ) {
    int i = t;
    int off = 0;
    for (int tt = 0; tt < i; ++tt) {
      int lo = tt - KW; if (lo < 0) lo = 0;
      int hi = tt + KW; if (hi > LSEQ - 1) hi = LSEQ - 1;
      off += hi - lo + 1;
    }
    int jlo = i - KW; if (jlo < 0) jlo = 0;
    int jhi = i + KW; if (jhi > LSEQ - 1) jhi = LSEQ - 1;
    for (int j = jlo; j <= jhi; ++j) {
      int p = off + (j - jlo);
      tab_i[p] = i; tab_j[p] = j; tab_r[p] = j - i;
      out_pos[2 * p]     = (float)(i + 1);
      out_pos[2 * p + 1] = (float)(j + 1);
    }
  }
  // smoothed17[r][d] = sum_s (128-|s-8|) * exp(-(r-s)^2) * pos_emb[s][d]
  for (int idx = t; idx < 17 * 64; idx += 256) {
    int r = idx >> 6, d = idx & 63;
    float acc = 0.f;
    for (int s = 0; s < 17; ++s) {
      float diff = (float)(r - s);
      int a = s - 8; if (a < 0) a = -a;
      float cnt = (float)(128 - a);
      acc += cnt * expf(-diff * diff) * pos_emb[s * 64 + d];
    }
    sm17[idx] = f2bf(acc);
  }
  for (int g = t; g < GPAD; g += 256) {
    b1p[g] = (g < FDIM) ? b1[g] : 0.f;
    w2p[g] = (g < FDIM) ? W2[g] : 0.f;
  }
}

// ---- fused GEMM: pred[r] += sum_g relu(couples[r]·W1[g] + b1[g]) * W2[g] ----
__global__ __launch_bounds__(256, 2)
void pair_gemm(const u16* __restrict__ emoB, const u16* __restrict__ cauB,
               const u16* __restrict__ smB, const u16* __restrict__ W1p,
               const float* __restrict__ b1p, const float* __restrict__ w2p,
               const int* __restrict__ tab_i, const int* __restrict__ tab_j,
               const int* __restrict__ tab_r,
               float* __restrict__ pred) {
  __shared__ u16 As[128 * 32];
  __shared__ u16 Bs[128 * 32];
  __shared__ u32 offE[128], offC[128], offS[128];
  __shared__ float predAcc[2][128];

  const int tid = threadIdx.x;
  const int mblk = blockIdx.x;

  if (tid < 128) {
    int r = mblk * 128 + tid;
    int b = r / NP;
    int p = r - b * NP;
    offE[tid] = (u32)((b * LSEQ + tab_i[p]) * 512);
    offC[tid] = (u32)((b * LSEQ + tab_j[p]) * 512);
    offS[tid] = (u32)((tab_r[p] + KW) * 64);
    predAcc[0][tid] = 0.f;
    predAcc[1][tid] = 0.f;
  }
  __syncthreads();

  const int lane = tid & 63;
  const int w = tid >> 6;
  const int lrow = lane & 15;
  const int lk = (lane >> 4) * 8;
  const int wm = (w >> 1) * 64;  // wave row offset in tile
  const int wn = (w & 1) * 64;   // wave col offset in tile

  // staging thread mapping: inst0 covers rows [0,64), inst1 rows [64,128)
  const int row0 = tid >> 2;
  const int row1 = 64 + (tid >> 2);
  const int sub = (tid & 3) * 8;  // element offset within 32-elem row chunk
  const u32 e0 = offE[row0] + sub, e1 = offE[row1] + sub;
  const u32 c0 = offC[row0] + sub, c1 = offC[row1] + sub;
  const u32 s0 = offS[row0] + sub, s1 = offS[row1] + sub;
  const u32 bo0 = (u32)row0 * 1088 + sub, bo1 = (u32)row1 * 1088 + sub;

  char* AsB = (char*)&As[0] + w * 1024;
  char* BsB = (char*)&Bs[0] + w * 1024;

  for (int gi = 0; gi < 3; ++gi) {
    const int gbase = (blockIdx.y * 3 + gi) * 128;
    const u16* w1g = W1p + (size_t)gbase * 1088;

    f32x4 acc[4][4];
#pragma unroll
    for (int mi = 0; mi < 4; ++mi)
#pragma unroll
      for (int ni = 0; ni < 4; ++ni) acc[mi][ni] = (f32x4){0.f, 0.f, 0.f, 0.f};

    for (int ks = 0; ks < 34; ++ks) {
      const int f0 = ks * 32;
      const u16 *pa0, *pa1;
      if (f0 < 512)        { pa0 = emoB + e0 + f0;          pa1 = emoB + e1 + f0; }
      else if (f0 < 1024)  { pa0 = cauB + c0 + (f0 - 512);  pa1 = cauB + c1 + (f0 - 512); }
      else                 { pa0 = smB + s0 + (f0 - 1024);  pa1 = smB + s1 + (f0 - 1024); }
      load_lds16(pa0, AsB);
      load_lds16(pa1, AsB + 4096);
      load_lds16(w1g + bo0 + f0, BsB);
      load_lds16(w1g + bo1 + f0, BsB + 4096);
      __syncthreads();

      bf16x8 av[4], bv[4];
#pragma unroll
      for (int mi = 0; mi < 4; ++mi)
        av[mi] = *(const bf16x8*)&As[(wm + mi * 16 + lrow) * 32 + lk];
#pragma unroll
      for (int ni = 0; ni < 4; ++ni)
        bv[ni] = *(const bf16x8*)&Bs[(wn + ni * 16 + lrow) * 32 + lk];
#pragma unroll
      for (int mi = 0; mi < 4; ++mi)
#pragma unroll
        for (int ni = 0; ni < 4; ++ni)
          acc[mi][ni] = __builtin_amdgcn_mfma_f32_16x16x32_bf16(av[mi], bv[ni], acc[mi][ni], 0, 0, 0);
      __syncthreads();
    }

    // epilogue: relu(+b1) then dot with W2, reduce over g-cols
    float rs[4][4];
#pragma unroll
    for (int mi = 0; mi < 4; ++mi)
#pragma unroll
      for (int r2 = 0; r2 < 4; ++r2) rs[mi][r2] = 0.f;

#pragma unroll
    for (int ni = 0; ni < 4; ++ni) {
      int g = gbase + wn + ni * 16 + lrow;
      float w2v = w2p[g];
      float b1v = b1p[g];
#pragma unroll
      for (int mi = 0; mi < 4; ++mi)
#pragma unroll
        for (int r2 = 0; r2 < 4; ++r2) {
          float hv = acc[mi][ni][r2] + b1v;
          hv = fmaxf(hv, 0.f);
          rs[mi][r2] += hv * w2v;
        }
    }
#pragma unroll
    for (int mi = 0; mi < 4; ++mi)
#pragma unroll
      for (int r2 = 0; r2 < 4; ++r2) {
        float v2 = rs[mi][r2];
        v2 += __shfl_xor(v2, 1, 16);
        v2 += __shfl_xor(v2, 2, 16);
        v2 += __shfl_xor(v2, 4, 16);
        v2 += __shfl_xor(v2, 8, 16);
        if (lrow == 0)
          predAcc[w & 1][wm + mi * 16 + (lane >> 4) * 4 + r2] += v2;
      }
  }
  __syncthreads();
  if (tid < 128) {
    int r = mblk * 128 + tid;
    atomicAdd(&pred[r], predAcc[0][tid] + predAcc[1][tid]);
  }
}

extern "C" void kernel_launch(void* const* d_in, const int* in_sizes, int n_in,
                              void* d_out, int out_size, void* d_ws, size_t ws_size,
                              hipStream_t stream) {
  const float* h_emo = (const float*)d_in[0];
  const float* h_cau = (const float*)d_in[1];
  const float* pos_emb = (const float*)d_in[2];
  const float* W1 = (const float*)d_in[3];
  const float* b1 = (const float*)d_in[4];
  const float* W2 = (const float*)d_in[5];
  const float* b2 = (const float*)d_in[6];

  char* ws = (char*)d_ws;
  u16* W1p = (u16*)(ws + WS_W1P);
  u16* emoB = (u16*)(ws + WS_EMOB);
  u16* cauB = (u16*)(ws + WS_CAUB);
  u16* smB = (u16*)(ws + WS_SMB);
  float* b1p = (float*)(ws + WS_B1P);
  float* w2p = (float*)(ws + WS_W2P);
  int* tab_i = (int*)(ws + WS_TABI);
  int* tab_j = (int*)(ws + WS_TABJ);
  int* tab_r = (int*)(ws + WS_TABR);

  float* pred = (float*)d_out;
  float* out_pos = (float*)d_out + MTOT;

  cvt_w1<<<1224, 256, 0, stream>>>(W1, W1p);
  cvt_h<<<2081, 256, 0, stream>>>(h_emo, h_cau, b2, emoB, cauB, pred);
  setup_small<<<1, 256, 0, stream>>>(pos_emb, b1, W2, tab_i, tab_j, tab_r,
                                     smB, b1p, w2p, out_pos);
  pair_gemm<<<dim3(263, 3), 256, 0, stream>>>(emoB, cauB, smB, W1p, b1p, w2p,
                                              tab_i, tab_j, tab_r, pred);
}

// Round 2
// 172.075 us; speedup vs baseline: 1.0732x; 1.0732x over previous
//
#include <hip/hip_runtime.h>

typedef unsigned short u16;
typedef unsigned int u32;
typedef __attribute__((ext_vector_type(4))) float f32x4;
typedef __attribute__((ext_vector_type(8))) __bf16 bf16x8;
typedef __attribute__((ext_vector_type(4))) u16 u16x4;
typedef __attribute__((ext_vector_type(4))) float f32x4v;

#define LSEQ 128
#define KW 8
#define NP 2104
#define BATCH 16
#define MTOT 33664   // BATCH*NP = 263*128
#define FDIM 1088    // PAIR_FEAT
#define GPAD 1152    // 9*128

// ---- workspace layout (bytes) ----
#define WS_W1P  0ul          // u16 [1152*1088] = 2,506,752 B
#define WS_EMOB 2506752ul    // u16 [16*128*512] = 2,097,152 B
#define WS_CAUB 4603904ul    // u16 [16*128*512]
#define WS_SMB  6701056ul    // u16 [17*64] = 2,176 B
#define WS_B1P  6703232ul    // f32 [1152]
#define WS_W2P  6707840ul    // f32 [1152]
#define WS_TABI 6712448ul    // int [2104]
#define WS_TABJ 6720864ul    // int [2104]
#define WS_TABR 6729280ul    // int [2104]  (end 6,737,696)

__device__ __forceinline__ u16 f2bf(float x) {
  union { float f; u32 u; } v; v.f = x;
  u32 r = v.u + 0x7fffu + ((v.u >> 16) & 1u);
  return (u16)(r >> 16);
}

__device__ __forceinline__ void load_lds16(const void* g, void* l) {
  __builtin_amdgcn_global_load_lds(
      (const __attribute__((address_space(1))) void*)g,
      (__attribute__((address_space(3))) void*)l, 16, 0, 0);
}

// ---- fused setup: W1->bf16 pad, H->bf16, pred=b2 init, tables/sm17/b1p/w2p ----
// blockIdx.x: [0,1224)       -> W1 convert (313344 vec4 units)
//             [1224,3305)    -> H convert + pred init (532704 vec4 units)
//             3305           -> small setup (single block)
__global__ void setup_all(const float* __restrict__ emo, const float* __restrict__ cau,
                          const float* __restrict__ pos_emb, const float* __restrict__ W1,
                          const float* __restrict__ b1, const float* __restrict__ W2,
                          const float* __restrict__ b2,
                          u16* __restrict__ W1p, u16* __restrict__ emoB,
                          u16* __restrict__ cauB, u16* __restrict__ sm17,
                          float* __restrict__ b1p, float* __restrict__ w2p,
                          int* __restrict__ tab_i, int* __restrict__ tab_j,
                          int* __restrict__ tab_r,
                          float* __restrict__ pred, float* __restrict__ out_pos) {
  const int bx = blockIdx.x;
  const int t = threadIdx.x;
  if (bx < 1224) {
    int idx = bx * 256 + t;
    if (idx >= 313344) return;
    int g = idx / 272;
    int f = (idx - g * 272) * 4;
    u16x4 o;
    if (g < 1088) {
      f32x4v v = *(const f32x4v*)&W1[g * 1088 + f];
      o.x = f2bf(v.x); o.y = f2bf(v.y); o.z = f2bf(v.z); o.w = f2bf(v.w);
    } else {
      o.x = 0; o.y = 0; o.z = 0; o.w = 0;
    }
    *(u16x4*)&W1p[(size_t)g * 1088 + f] = o;
  } else if (bx < 3305) {
    int idx = (bx - 1224) * 256 + t;
    if (idx < 262144) {
      f32x4v v = *(const f32x4v*)&emo[idx * 4];
      u16x4 o; o.x = f2bf(v.x); o.y = f2bf(v.y); o.z = f2bf(v.z); o.w = f2bf(v.w);
      *(u16x4*)&emoB[idx * 4] = o;
    } else if (idx < 524288) {
      int k = idx - 262144;
      f32x4v v = *(const f32x4v*)&cau[k * 4];
      u16x4 o; o.x = f2bf(v.x); o.y = f2bf(v.y); o.z = f2bf(v.z); o.w = f2bf(v.w);
      *(u16x4*)&cauB[k * 4] = o;
    } else {
      int k = idx - 524288;      // 8416 vec4 units cover 33664 floats
      if (k < 8416) {
        float bv = b2[0];
        f32x4v o = {bv, bv, bv, bv};
        *(f32x4v*)&pred[k * 4] = o;
      }
    }
  } else {
    if (t < LSEQ) {
      int i = t;
      int off = 0;
      for (int tt = 0; tt < i; ++tt) {
        int lo = tt - KW; if (lo < 0) lo = 0;
        int hi = tt + KW; if (hi > LSEQ - 1) hi = LSEQ - 1;
        off += hi - lo + 1;
      }
      int jlo = i - KW; if (jlo < 0) jlo = 0;
      int jhi = i + KW; if (jhi > LSEQ - 1) jhi = LSEQ - 1;
      for (int j = jlo; j <= jhi; ++j) {
        int p = off + (j - jlo);
        tab_i[p] = i; tab_j[p] = j; tab_r[p] = j - i;
        out_pos[2 * p]     = (float)(i + 1);
        out_pos[2 * p + 1] = (float)(j + 1);
      }
    }
    // smoothed17[r][d] = sum_s (128-|s-8|) * exp(-(r-s)^2) * pos_emb[s][d]
    for (int idx = t; idx < 17 * 64; idx += 256) {
      int r = idx >> 6, d = idx & 63;
      float acc = 0.f;
      for (int s = 0; s < 17; ++s) {
        float diff = (float)(r - s);
        int a = s - 8; if (a < 0) a = -a;
        float cnt = (float)(128 - a);
        acc += cnt * expf(-diff * diff) * pos_emb[s * 64 + d];
      }
      sm17[idx] = f2bf(acc);
    }
    for (int g = t; g < GPAD; g += 256) {
      b1p[g] = (g < FDIM) ? b1[g] : 0.f;
      w2p[g] = (g < FDIM) ? W2[g] : 0.f;
    }
  }
}

// ---- fused GEMM: pred[r] += sum_g relu(couples[r]·W1[g] + b1[g]) * W2[g] ----
// grid (263 m-tiles, 9 g-tiles); one 128-col g-tile per block for occupancy
__global__ __launch_bounds__(256, 2)
void pair_gemm(const u16* __restrict__ emoB, const u16* __restrict__ cauB,
               const u16* __restrict__ smB, const u16* __restrict__ W1p,
               const float* __restrict__ b1p, const float* __restrict__ w2p,
               const int* __restrict__ tab_i, const int* __restrict__ tab_j,
               const int* __restrict__ tab_r,
               float* __restrict__ pred) {
  __shared__ u16 As[128 * 32];
  __shared__ u16 Bs[128 * 32];
  __shared__ u32 offE[128], offC[128], offS[128];
  __shared__ float predAcc[2][128];

  const int tid = threadIdx.x;
  const int mblk = blockIdx.x;

  if (tid < 128) {
    int r = mblk * 128 + tid;
    int b = r / NP;
    int p = r - b * NP;
    offE[tid] = (u32)((b * LSEQ + tab_i[p]) * 512);
    offC[tid] = (u32)((b * LSEQ + tab_j[p]) * 512);
    offS[tid] = (u32)((tab_r[p] + KW) * 64);
    predAcc[0][tid] = 0.f;
    predAcc[1][tid] = 0.f;
  }
  __syncthreads();

  const int lane = tid & 63;
  const int w = tid >> 6;
  const int lrow = lane & 15;
  const int lk = (lane >> 4) * 8;
  const int wm = (w >> 1) * 64;  // wave row offset in tile
  const int wn = (w & 1) * 64;   // wave col offset in tile

  // staging thread mapping: inst0 covers rows [0,64), inst1 rows [64,128)
  const int row0 = tid >> 2;
  const int row1 = 64 + (tid >> 2);
  const int sub = (tid & 3) * 8;  // element offset within 32-elem row chunk
  const u32 e0 = offE[row0] + sub, e1 = offE[row1] + sub;
  const u32 c0 = offC[row0] + sub, c1 = offC[row1] + sub;
  const u32 s0 = offS[row0] + sub, s1 = offS[row1] + sub;
  const u32 bo0 = (u32)row0 * 1088 + sub, bo1 = (u32)row1 * 1088 + sub;

  char* AsB = (char*)&As[0] + w * 1024;
  char* BsB = (char*)&Bs[0] + w * 1024;

  const int gbase = blockIdx.y * 128;
  const u16* w1g = W1p + (size_t)gbase * 1088;

  f32x4 acc[4][4];
#pragma unroll
  for (int mi = 0; mi < 4; ++mi)
#pragma unroll
    for (int ni = 0; ni < 4; ++ni) acc[mi][ni] = (f32x4){0.f, 0.f, 0.f, 0.f};

  for (int ks = 0; ks < 34; ++ks) {
    const int f0 = ks * 32;
    const u16 *pa0, *pa1;
    if (f0 < 512)        { pa0 = emoB + e0 + f0;          pa1 = emoB + e1 + f0; }
    else if (f0 < 1024)  { pa0 = cauB + c0 + (f0 - 512);  pa1 = cauB + c1 + (f0 - 512); }
    else                 { pa0 = smB + s0 + (f0 - 1024);  pa1 = smB + s1 + (f0 - 1024); }
    load_lds16(pa0, AsB);
    load_lds16(pa1, AsB + 4096);
    load_lds16(w1g + bo0 + f0, BsB);
    load_lds16(w1g + bo1 + f0, BsB + 4096);
    __syncthreads();

    bf16x8 av[4], bv[4];
#pragma unroll
    for (int mi = 0; mi < 4; ++mi)
      av[mi] = *(const bf16x8*)&As[(wm + mi * 16 + lrow) * 32 + lk];
#pragma unroll
    for (int ni = 0; ni < 4; ++ni)
      bv[ni] = *(const bf16x8*)&Bs[(wn + ni * 16 + lrow) * 32 + lk];
#pragma unroll
    for (int mi = 0; mi < 4; ++mi)
#pragma unroll
      for (int ni = 0; ni < 4; ++ni)
        acc[mi][ni] = __builtin_amdgcn_mfma_f32_16x16x32_bf16(av[mi], bv[ni], acc[mi][ni], 0, 0, 0);
    __syncthreads();
  }

  // epilogue: relu(+b1) then dot with W2, reduce over g-cols
  float rs[4][4];
#pragma unroll
  for (int mi = 0; mi < 4; ++mi)
#pragma unroll
    for (int r2 = 0; r2 < 4; ++r2) rs[mi][r2] = 0.f;

#pragma unroll
  for (int ni = 0; ni < 4; ++ni) {
    int g = gbase + wn + ni * 16 + lrow;
    float w2v = w2p[g];
    float b1v = b1p[g];
#pragma unroll
    for (int mi = 0; mi < 4; ++mi)
#pragma unroll
      for (int r2 = 0; r2 < 4; ++r2) {
        float hv = acc[mi][ni][r2] + b1v;
        hv = fmaxf(hv, 0.f);
        rs[mi][r2] += hv * w2v;
      }
  }
#pragma unroll
  for (int mi = 0; mi < 4; ++mi)
#pragma unroll
    for (int r2 = 0; r2 < 4; ++r2) {
      float v2 = rs[mi][r2];
      v2 += __shfl_xor(v2, 1, 16);
      v2 += __shfl_xor(v2, 2, 16);
      v2 += __shfl_xor(v2, 4, 16);
      v2 += __shfl_xor(v2, 8, 16);
      if (lrow == 0)
        predAcc[w & 1][wm + mi * 16 + (lane >> 4) * 4 + r2] += v2;
    }
  __syncthreads();
  if (tid < 128) {
    int r = mblk * 128 + tid;
    atomicAdd(&pred[r], predAcc[0][tid] + predAcc[1][tid]);
  }
}

extern "C" void kernel_launch(void* const* d_in, const int* in_sizes, int n_in,
                              void* d_out, int out_size, void* d_ws, size_t ws_size,
                              hipStream_t stream) {
  const float* h_emo = (const float*)d_in[0];
  const float* h_cau = (const float*)d_in[1];
  const float* pos_emb = (const float*)d_in[2];
  const float* W1 = (const float*)d_in[3];
  const float* b1 = (const float*)d_in[4];
  const float* W2 = (const float*)d_in[5];
  const float* b2 = (const float*)d_in[6];

  char* ws = (char*)d_ws;
  u16* W1p = (u16*)(ws + WS_W1P);
  u16* emoB = (u16*)(ws + WS_EMOB);
  u16* cauB = (u16*)(ws + WS_CAUB);
  u16* smB = (u16*)(ws + WS_SMB);
  float* b1p = (float*)(ws + WS_B1P);
  float* w2p = (float*)(ws + WS_W2P);
  int* tab_i = (int*)(ws + WS_TABI);
  int* tab_j = (int*)(ws + WS_TABJ);
  int* tab_r = (int*)(ws + WS_TABR);

  float* pred = (float*)d_out;
  float* out_pos = (float*)d_out + MTOT;

  setup_all<<<3306, 256, 0, stream>>>(h_emo, h_cau, pos_emb, W1, b1, W2, b2,
                                      W1p, emoB, cauB, smB, b1p, w2p,
                                      tab_i, tab_j, tab_r, pred, out_pos);
  pair_gemm<<<dim3(263, 9), 256, 0, stream>>>(emoB, cauB, smB, W1p, b1p, w2p,
                                              tab_i, tab_j, tab_r, pred);
}